// Round 1
// baseline (839.378 us; speedup 1.0000x reference)
//
#include <hip/hip_runtime.h>

#define N_NODES 50000
#define N_EDGES 800000
#define HID 64
#define N_LAYERS 3
#define N_GRAPHS 64

// u[l][h'] = sum_h edge_w[l][h] * node_w[l][HID+h][h']
// v[l][h'] = sum_h edge_b[l][h] * node_w[l][HID+h][h']
__global__ void uv_kernel(const float* __restrict__ edge_w, const float* __restrict__ edge_b,
                          const float* __restrict__ node_w, float* __restrict__ uv) {
    int tid = blockIdx.x * blockDim.x + threadIdx.x;
    if (tid >= N_LAYERS * HID) return;
    int l = tid >> 6, hp = tid & 63;
    const float* w2 = node_w + l * 2 * HID * HID + HID * HID + hp; // [l][HID+h][hp], stride HID in h
    float u = 0.f, v = 0.f;
    for (int h = 0; h < HID; h++) {
        float w = w2[h * HID];
        u += edge_w[l * HID + h] * w;
        v += edge_b[l * HID + h] * w;
    }
    uv[l * 2 * HID + hp]       = u;
    uv[l * 2 * HID + HID + hp] = v;
}

// deg[n] = in-degree, sattr[n] = sum of edge_attr into n  (layer-invariant)
__global__ void edge_stats_kernel(const int* __restrict__ dst, const float* __restrict__ ea,
                                  float* __restrict__ deg, float* __restrict__ sattr) {
    int e = blockIdx.x * blockDim.x + threadIdx.x;
    if (e >= N_EDGES) return;
    int d = dst[e];
    atomicAdd(&deg[d], 1.0f);
    atomicAdd(&sattr[d], ea[e]);
}

// one wave per edge, lane = feature: aggr[dst] += x[src]
__global__ __launch_bounds__(256) void scatter_kernel(const float* __restrict__ x,
                                                      const int* __restrict__ src,
                                                      const int* __restrict__ dst,
                                                      float* __restrict__ aggr) {
    int gid = blockIdx.x * blockDim.x + threadIdx.x;
    int e = gid >> 6;
    int lane = threadIdx.x & 63;
    if (e >= N_EDGES) return;
    int s = src[e], d = dst[e];
    float v = x[s * HID + lane];
    atomicAdd(&aggr[d * HID + lane], v);
}

// x_out[n][h'] = relu( sum_h aggr[n][h]*W1[h][h'] + sattr[n]*u[h'] + deg[n]*v[h'] + b[h'] )
__global__ __launch_bounds__(256) void update_kernel(const float* __restrict__ aggr,
                                                     const float* __restrict__ node_w_l,
                                                     const float* __restrict__ node_b_l,
                                                     const float* __restrict__ uv_l,
                                                     const float* __restrict__ deg,
                                                     const float* __restrict__ sattr,
                                                     float* __restrict__ xout) {
    __shared__ float Wl[HID * HID];   // 16 KB: first HID rows of node_w[l]
    __shared__ float rows[4][HID];
    int tid = threadIdx.x;
    for (int i = tid; i < HID * HID; i += 256) Wl[i] = node_w_l[i];
    int i = tid >> 6, hp = tid & 63;
    int n = blockIdx.x * 4 + i;
    if (n < N_NODES) rows[i][hp] = aggr[n * HID + hp];
    __syncthreads();
    if (n >= N_NODES) return;
    float sum = 0.f;
#pragma unroll
    for (int h = 0; h < HID; h++) sum += rows[i][h] * Wl[h * HID + hp];
    sum += sattr[n] * uv_l[hp] + deg[n] * uv_l[HID + hp] + node_b_l[hp];
    xout[n * HID + hp] = sum > 0.f ? sum : 0.f;  // relu; leaky-relu of relu output = identity
}

// batch is sorted: run-length accumulate in registers, flush with atomics on graph change
__global__ void pool_kernel(const float* __restrict__ x, const int* __restrict__ batch,
                            float* __restrict__ sums, float* __restrict__ counts) {
    const int CHUNK = 128;
    int lane = threadIdx.x;  // blockDim = 64
    int n0 = blockIdx.x * CHUNK;
    int n1 = n0 + CHUNK; if (n1 > N_NODES) n1 = N_NODES;
    float acc = 0.f; int curg = -1; int run = 0;
    for (int n = n0; n < n1; n++) {
        int g = batch[n];
        if (g != curg) {
            if (curg >= 0) {
                atomicAdd(&sums[curg * HID + lane], acc);
                if (lane == 0) atomicAdd(&counts[curg], (float)run);
            }
            curg = g; acc = 0.f; run = 0;
        }
        acc += x[n * HID + lane];
        run++;
    }
    if (curg >= 0) {
        atomicAdd(&sums[curg * HID + lane], acc);
        if (lane == 0) atomicAdd(&counts[curg], (float)run);
    }
}

__global__ void final_kernel(const float* __restrict__ sums, const float* __restrict__ counts,
                             const float* __restrict__ fc_w, const float* __restrict__ fc_b,
                             float* __restrict__ out) {
    int g = threadIdx.x;
    if (g >= N_GRAPHS) return;
    float dot = 0.f;
    for (int h = 0; h < HID; h++) dot += sums[g * HID + h] * fc_w[h];
    float cnt = counts[g]; if (cnt < 1.f) cnt = 1.f;
    out[g] = dot / cnt + fc_b[0];
}

extern "C" void kernel_launch(void* const* d_in, const int* in_sizes, int n_in,
                              void* d_out, int out_size, void* d_ws, size_t ws_size,
                              hipStream_t stream) {
    const float* x_in      = (const float*)d_in[0];
    const float* edge_attr = (const float*)d_in[1];
    const float* edge_w    = (const float*)d_in[2];
    const float* edge_b    = (const float*)d_in[3];
    const float* node_w    = (const float*)d_in[4];
    const float* node_b    = (const float*)d_in[5];
    const float* fc_w      = (const float*)d_in[6];
    const float* fc_b      = (const float*)d_in[7];
    const int*   edge_index= (const int*)d_in[8];
    const int*   batch     = (const int*)d_in[9];
    float* out = (float*)d_out;

    // workspace layout (floats): aggr[N*H] | xA[N*H] | deg[N] | sattr[N] | uv[L*2*H] | sums[G*H] | counts[G]
    float* ws     = (float*)d_ws;
    float* aggr   = ws;
    float* xA     = aggr + (size_t)N_NODES * HID;
    float* deg    = xA + (size_t)N_NODES * HID;
    float* sattr  = deg + N_NODES;
    float* uv     = sattr + N_NODES;
    float* sums   = uv + N_LAYERS * 2 * HID;
    float* counts = sums + N_GRAPHS * HID;
    // total ~26 MB

    const int* src = edge_index;            // edge_index[0]
    const int* dst = edge_index + N_EDGES;  // edge_index[1]

    // zero deg/sattr/uv/sums/counts (contiguous region)
    size_t zcount = 2 * (size_t)N_NODES + N_LAYERS * 2 * HID + N_GRAPHS * HID + N_GRAPHS;
    hipMemsetAsync(deg, 0, zcount * sizeof(float), stream);

    uv_kernel<<<1, 256, 0, stream>>>(edge_w, edge_b, node_w, uv);
    edge_stats_kernel<<<(N_EDGES + 255) / 256, 256, 0, stream>>>(dst, edge_attr, deg, sattr);

    const float* xin = x_in;
    for (int l = 0; l < N_LAYERS; l++) {
        hipMemsetAsync(aggr, 0, (size_t)N_NODES * HID * sizeof(float), stream);
        scatter_kernel<<<(N_EDGES * 64) / 256, 256, 0, stream>>>(xin, src, dst, aggr);
        update_kernel<<<(N_NODES + 3) / 4, 256, 0, stream>>>(
            aggr, node_w + (size_t)l * 2 * HID * HID, node_b + l * HID, uv + l * 2 * HID,
            deg, sattr, xA);
        xin = xA;
    }

    pool_kernel<<<(N_NODES + 127) / 128, 64, 0, stream>>>(xA, batch, sums, counts);
    final_kernel<<<1, 64, 0, stream>>>(sums, counts, fc_w, fc_b, out);
}

// Round 2
// 611.459 us; speedup vs baseline: 1.3727x; 1.3727x over previous
//
#include <hip/hip_runtime.h>

#define N_NODES 50000
#define N_EDGES 800000
#define HID 64
#define N_LAYERS 3
#define N_GRAPHS 64
#define SCAN_T 1024

// u[l][h'] = sum_h edge_w[l][h] * node_w[l][HID+h][h']   (fold edge-MLP through W2)
// v[l][h'] = sum_h edge_b[l][h] * node_w[l][HID+h][h']
__global__ void uv_kernel(const float* __restrict__ edge_w, const float* __restrict__ edge_b,
                          const float* __restrict__ node_w, float* __restrict__ uv) {
    int tid = blockIdx.x * blockDim.x + threadIdx.x;
    if (tid >= N_LAYERS * HID) return;
    int l = tid >> 6, hp = tid & 63;
    const float* w2 = node_w + l * 2 * HID * HID + HID * HID + hp;
    float u = 0.f, v = 0.f;
    for (int h = 0; h < HID; h++) {
        float w = w2[h * HID];
        u += edge_w[l * HID + h] * w;
        v += edge_b[l * HID + h] * w;
    }
    uv[l * 2 * HID + hp]       = u;
    uv[l * 2 * HID + HID + hp] = v;
}

// hist[d]++ (int) and sattr[d] += edge_attr[e]  (both layer-invariant)
__global__ void edge_stats_kernel(const int* __restrict__ dst, const float* __restrict__ ea,
                                  int* __restrict__ hist, float* __restrict__ sattr) {
    int e = blockIdx.x * blockDim.x + threadIdx.x;
    if (e >= N_EDGES) return;
    int d = dst[e];
    atomicAdd(&hist[d], 1);
    atomicAdd(&sattr[d], ea[e]);
}

// single-block exclusive scan of hist -> rowptr[0..N], cursor copy for the build
__global__ __launch_bounds__(SCAN_T) void scan_kernel(const int* __restrict__ hist,
                                                      int* __restrict__ rowptr,
                                                      int* __restrict__ cursor) {
    __shared__ int psum[SCAN_T];
    int t = threadIdx.x;
    const int CH = (N_NODES + SCAN_T - 1) / SCAN_T;
    int lo = t * CH, hi = lo + CH; if (hi > N_NODES) hi = N_NODES;
    int s = 0;
    for (int i = lo; i < hi; i++) s += hist[i];
    psum[t] = s;
    __syncthreads();
    for (int off = 1; off < SCAN_T; off <<= 1) {
        int add = (t >= off) ? psum[t - off] : 0;
        __syncthreads();
        psum[t] += add;
        __syncthreads();
    }
    int run = psum[t] - s;  // exclusive prefix of this thread's chunk
    for (int i = lo; i < hi; i++) {
        rowptr[i] = run; cursor[i] = run;
        run += hist[i];
    }
    if (t == SCAN_T - 1) rowptr[N_NODES] = run;  // == N_EDGES
}

// bucket-scatter src ids into CSR order
__global__ void build_kernel(const int* __restrict__ src, const int* __restrict__ dst,
                             int* __restrict__ cursor, int* __restrict__ esrc) {
    int e = blockIdx.x * blockDim.x + threadIdx.x;
    if (e >= N_EDGES) return;
    int pos = atomicAdd(&cursor[dst[e]], 1);
    esrc[pos] = src[e];
}

// Fused aggregate + node update. One wave per node (grid-stride), lane = out feature.
// Each wave keeps its column of W1 (node_w first half) in 64 VGPRs.
// x_out[n][hp] = relu( sum_h (sum_{e->n} x[src_e][h]) * W1[h][hp]
//                      + sattr[n]*u[hp] + deg[n]*v[hp] + b[hp] )
__global__ __launch_bounds__(256) void agg_update_kernel(
        const float* __restrict__ x, const int* __restrict__ esrc,
        const int* __restrict__ rowptr, const float* __restrict__ W1,
        const float* __restrict__ node_b_l, const float* __restrict__ uv_l,
        const float* __restrict__ sattr, float* __restrict__ xout) {
    int lane = threadIdx.x & 63;
    int wave = (blockIdx.x * blockDim.x + threadIdx.x) >> 6;
    int nwaves = (gridDim.x * blockDim.x) >> 6;

    float wcol[HID];  // W1[h][lane] for all h — column held in registers
#pragma unroll
    for (int h = 0; h < HID; h++) wcol[h] = W1[h * HID + lane];
    float uL = uv_l[lane], vL = uv_l[HID + lane], bL = node_b_l[lane];

    for (int n = wave; n < N_NODES; n += nwaves) {
        int beg = rowptr[n], end = rowptr[n + 1];
        float acc = 0.f;
        int j = beg;
        for (; j + 1 < end; j += 2) {   // unroll-2: two loads in flight
            int s0 = esrc[j], s1 = esrc[j + 1];
            float a0 = x[s0 * HID + lane];
            float a1 = x[s1 * HID + lane];
            acc += a0; acc += a1;
        }
        if (j < end) acc += x[esrc[j] * HID + lane];

        float sum = 0.f;
#pragma unroll
        for (int h = 0; h < HID; h++)
            sum += __shfl(acc, h) * wcol[h];   // readlane broadcast × reg column

        float dg = (float)(end - beg);
        sum += sattr[n] * uL + dg * vL + bL;
        xout[n * HID + lane] = sum > 0.f ? sum : 0.f;  // relu (leaky of relu = identity)
    }
}

// batch is sorted: run-length accumulate in registers, flush on graph change
__global__ void pool_kernel(const float* __restrict__ x, const int* __restrict__ batch,
                            float* __restrict__ sums, float* __restrict__ counts) {
    const int CHUNK = 128;
    int lane = threadIdx.x;  // blockDim = 64
    int n0 = blockIdx.x * CHUNK;
    int n1 = n0 + CHUNK; if (n1 > N_NODES) n1 = N_NODES;
    float acc = 0.f; int curg = -1; int run = 0;
    for (int n = n0; n < n1; n++) {
        int g = batch[n];
        if (g != curg) {
            if (curg >= 0) {
                atomicAdd(&sums[curg * HID + lane], acc);
                if (lane == 0) atomicAdd(&counts[curg], (float)run);
            }
            curg = g; acc = 0.f; run = 0;
        }
        acc += x[n * HID + lane];
        run++;
    }
    if (curg >= 0) {
        atomicAdd(&sums[curg * HID + lane], acc);
        if (lane == 0) atomicAdd(&counts[curg], (float)run);
    }
}

__global__ void final_kernel(const float* __restrict__ sums, const float* __restrict__ counts,
                             const float* __restrict__ fc_w, const float* __restrict__ fc_b,
                             float* __restrict__ out) {
    int g = threadIdx.x;
    if (g >= N_GRAPHS) return;
    float dot = 0.f;
    for (int h = 0; h < HID; h++) dot += sums[g * HID + h] * fc_w[h];
    float cnt = counts[g]; if (cnt < 1.f) cnt = 1.f;
    out[g] = dot / cnt + fc_b[0];
}

extern "C" void kernel_launch(void* const* d_in, const int* in_sizes, int n_in,
                              void* d_out, int out_size, void* d_ws, size_t ws_size,
                              hipStream_t stream) {
    const float* x_in      = (const float*)d_in[0];
    const float* edge_attr = (const float*)d_in[1];
    const float* edge_w    = (const float*)d_in[2];
    const float* edge_b    = (const float*)d_in[3];
    const float* node_w    = (const float*)d_in[4];
    const float* node_b    = (const float*)d_in[5];
    const float* fc_w      = (const float*)d_in[6];
    const float* fc_b      = (const float*)d_in[7];
    const int*   edge_index= (const int*)d_in[8];
    const int*   batch     = (const int*)d_in[9];
    float* out = (float*)d_out;

    // workspace layout (4B units):
    // xA[N*H] | xB[N*H] | esrc[E] | rowptr[N+1] | cursor[N] | hist[N] | sattr[N] | uv | sums | counts
    float* xA     = (float*)d_ws;
    float* xB     = xA + (size_t)N_NODES * HID;
    int*   esrc   = (int*)(xB + (size_t)N_NODES * HID);
    int*   rowptr = esrc + N_EDGES;
    int*   cursor = rowptr + N_NODES + 1;
    int*   hist   = cursor + N_NODES;
    float* sattr  = (float*)(hist + N_NODES);
    float* uv     = sattr + N_NODES;
    float* sums   = uv + N_LAYERS * 2 * HID;
    float* counts = sums + N_GRAPHS * HID;
    // total ~29.5 MB

    const int* src = edge_index;            // edge_index[0]
    const int* dst = edge_index + N_EDGES;  // edge_index[1]

    // zero hist | sattr | uv | sums | counts (contiguous)
    size_t zcount = 2 * (size_t)N_NODES + N_LAYERS * 2 * HID + (size_t)N_GRAPHS * HID + N_GRAPHS;
    hipMemsetAsync(hist, 0, zcount * sizeof(float), stream);

    uv_kernel<<<1, 256, 0, stream>>>(edge_w, edge_b, node_w, uv);
    edge_stats_kernel<<<(N_EDGES + 255) / 256, 256, 0, stream>>>(dst, edge_attr, hist, sattr);
    scan_kernel<<<1, SCAN_T, 0, stream>>>(hist, rowptr, cursor);
    build_kernel<<<(N_EDGES + 255) / 256, 256, 0, stream>>>(src, dst, cursor, esrc);

    // 3 fused layers, ping-pong x buffers
    const int AGG_BLOCKS = 1024;  // 4096 waves -> ~12 nodes/wave grid-stride
    const float* xin = x_in;
    float* bufs[2] = { xA, xB };
    for (int l = 0; l < N_LAYERS; l++) {
        float* xo = bufs[l & 1];
        agg_update_kernel<<<AGG_BLOCKS, 256, 0, stream>>>(
            xin, esrc, rowptr,
            node_w + (size_t)l * 2 * HID * HID, node_b + l * HID, uv + l * 2 * HID,
            sattr, xo);
        xin = xo;
    }

    pool_kernel<<<(N_NODES + 127) / 128, 64, 0, stream>>>(xA, batch, sums, counts);
    final_kernel<<<1, 64, 0, stream>>>(sums, counts, fc_w, fc_b, out);
}

// Round 3
// 474.431 us; speedup vs baseline: 1.7692x; 1.2888x over previous
//
#include <hip/hip_runtime.h>

#define N_NODES 50000
#define N_EDGES 800000
#define HID 64
#define N_LAYERS 3
#define N_GRAPHS 64

#define SCAN_B 256                                  // threads per scan block
#define SCAN_NB ((N_NODES + SCAN_B - 1) / SCAN_B)   // 196 blocks (covers 50176)

// u[l][h'] = sum_h edge_w[l][h] * node_w[l][HID+h][h']   (fold edge-MLP through W2)
// v[l][h'] = sum_h edge_b[l][h] * node_w[l][HID+h][h']
__global__ void uv_kernel(const float* __restrict__ edge_w, const float* __restrict__ edge_b,
                          const float* __restrict__ node_w, float* __restrict__ uv) {
    int tid = blockIdx.x * blockDim.x + threadIdx.x;
    if (tid >= N_LAYERS * HID) return;
    int l = tid >> 6, hp = tid & 63;
    const float* w2 = node_w + l * 2 * HID * HID + HID * HID + hp;
    float u = 0.f, v = 0.f;
    for (int h = 0; h < HID; h++) {
        float w = w2[h * HID];
        u += edge_w[l * HID + h] * w;
        v += edge_b[l * HID + h] * w;
    }
    uv[l * 2 * HID + hp]       = u;
    uv[l * 2 * HID + HID + hp] = v;
}

// hist[d]++ (int) and sattr[d] += edge_attr[e]  (both layer-invariant)
__global__ void edge_stats_kernel(const int* __restrict__ dst, const float* __restrict__ ea,
                                  int* __restrict__ hist, float* __restrict__ sattr) {
    int e = blockIdx.x * blockDim.x + threadIdx.x;
    if (e >= N_EDGES) return;
    int d = dst[e];
    atomicAdd(&hist[d], 1);
    atomicAdd(&sattr[d], ea[e]);
}

// ---- hierarchical exclusive scan of hist[0..N_NODES) -> rowptr[0..N_NODES], cursor ----
__global__ __launch_bounds__(SCAN_B) void scan_bsum_kernel(const int* __restrict__ hist,
                                                           int* __restrict__ bsum) {
    int i = blockIdx.x * SCAN_B + threadIdx.x;
    int v = (i < N_NODES) ? hist[i] : 0;
    // wave reduce (64 lanes)
    for (int off = 32; off > 0; off >>= 1) v += __shfl_down(v, off);
    __shared__ int part[SCAN_B / 64];
    int wid = threadIdx.x >> 6;
    if ((threadIdx.x & 63) == 0) part[wid] = v;
    __syncthreads();
    if (threadIdx.x == 0) {
        int t = 0;
        for (int w = 0; w < SCAN_B / 64; w++) t += part[w];
        bsum[blockIdx.x] = t;
    }
}

// single block: exclusive scan of bsum[0..SCAN_NB) -> boff
__global__ __launch_bounds__(SCAN_B) void scan_top_kernel(const int* __restrict__ bsum,
                                                          int* __restrict__ boff) {
    __shared__ int s[SCAN_B];
    int t = threadIdx.x;
    int v = (t < SCAN_NB) ? bsum[t] : 0;
    s[t] = v;
    __syncthreads();
    for (int off = 1; off < SCAN_B; off <<= 1) {
        int add = (t >= off) ? s[t - off] : 0;
        __syncthreads();
        s[t] += add;
        __syncthreads();
    }
    if (t < SCAN_NB) boff[t] = s[t] - v;  // exclusive
}

// apply: rowptr[i] = boff[b] + local exclusive prefix; also cursor copy; rowptr[N]=E
__global__ __launch_bounds__(SCAN_B) void scan_apply_kernel(const int* __restrict__ hist,
                                                            const int* __restrict__ boff,
                                                            int* __restrict__ rowptr,
                                                            int* __restrict__ cursor) {
    __shared__ int s[SCAN_B];
    int t = threadIdx.x;
    int i = blockIdx.x * SCAN_B + t;
    int v = (i < N_NODES) ? hist[i] : 0;
    s[t] = v;
    __syncthreads();
    for (int off = 1; off < SCAN_B; off <<= 1) {
        int add = (t >= off) ? s[t - off] : 0;
        __syncthreads();
        s[t] += add;
        __syncthreads();
    }
    int excl = boff[blockIdx.x] + s[t] - v;
    if (i < N_NODES) { rowptr[i] = excl; cursor[i] = excl; }
    else if (i == N_NODES) rowptr[N_NODES] = excl;  // == N_EDGES
}

// bucket-scatter src ids into CSR order
__global__ void build_kernel(const int* __restrict__ src, const int* __restrict__ dst,
                             int* __restrict__ cursor, int* __restrict__ esrc) {
    int e = blockIdx.x * blockDim.x + threadIdx.x;
    if (e >= N_EDGES) return;
    int pos = atomicAdd(&cursor[dst[e]], 1);
    esrc[pos] = src[e];
}

// Fused aggregate + node update. One wave handles NPW contiguous nodes; lane = out feature.
// Each wave keeps its column of W1 in 64 VGPRs.
#define NPW 4
__global__ __launch_bounds__(256) void agg_update_kernel(
        const float* __restrict__ x, const int* __restrict__ esrc,
        const int* __restrict__ rowptr, const float* __restrict__ W1,
        const float* __restrict__ node_b_l, const float* __restrict__ uv_l,
        const float* __restrict__ sattr, float* __restrict__ xout) {
    int lane = threadIdx.x & 63;
    int wave = (blockIdx.x * blockDim.x + threadIdx.x) >> 6;
    int n0 = wave * NPW;
    if (n0 >= N_NODES) return;
    int n1 = n0 + NPW; if (n1 > N_NODES) n1 = N_NODES;

    float wcol[HID];  // W1[h][lane]
#pragma unroll
    for (int h = 0; h < HID; h++) wcol[h] = W1[h * HID + lane];
    float uL = uv_l[lane], vL = uv_l[HID + lane], bL = node_b_l[lane];

    for (int n = n0; n < n1; n++) {
        int beg = rowptr[n], end = rowptr[n + 1];
        float acc = 0.f;
        int j = beg;
        for (; j + 3 < end; j += 4) {     // 4 independent gather chains in flight
            int s0 = esrc[j], s1 = esrc[j + 1], s2 = esrc[j + 2], s3 = esrc[j + 3];
            float a0 = x[s0 * HID + lane];
            float a1 = x[s1 * HID + lane];
            float a2 = x[s2 * HID + lane];
            float a3 = x[s3 * HID + lane];
            acc += a0; acc += a1; acc += a2; acc += a3;
        }
        for (; j < end; j++) acc += x[esrc[j] * HID + lane];

        float sum = 0.f;
#pragma unroll
        for (int h = 0; h < HID; h++)
            sum += __shfl(acc, h) * wcol[h];   // readlane broadcast × reg column

        float dg = (float)(end - beg);
        sum += sattr[n] * uL + dg * vL + bL;
        xout[n * HID + lane] = sum > 0.f ? sum : 0.f;  // relu (leaky of relu = identity)
    }
}

// batch is sorted: run-length accumulate in registers, flush on graph change
__global__ void pool_kernel(const float* __restrict__ x, const int* __restrict__ batch,
                            float* __restrict__ sums, float* __restrict__ counts) {
    const int CHUNK = 128;
    int lane = threadIdx.x;  // blockDim = 64
    int n0 = blockIdx.x * CHUNK;
    int n1 = n0 + CHUNK; if (n1 > N_NODES) n1 = N_NODES;
    float acc = 0.f; int curg = -1; int run = 0;
    for (int n = n0; n < n1; n++) {
        int g = batch[n];
        if (g != curg) {
            if (curg >= 0) {
                atomicAdd(&sums[curg * HID + lane], acc);
                if (lane == 0) atomicAdd(&counts[curg], (float)run);
            }
            curg = g; acc = 0.f; run = 0;
        }
        acc += x[n * HID + lane];
        run++;
    }
    if (curg >= 0) {
        atomicAdd(&sums[curg * HID + lane], acc);
        if (lane == 0) atomicAdd(&counts[curg], (float)run);
    }
}

__global__ void final_kernel(const float* __restrict__ sums, const float* __restrict__ counts,
                             const float* __restrict__ fc_w, const float* __restrict__ fc_b,
                             float* __restrict__ out) {
    int g = threadIdx.x;
    if (g >= N_GRAPHS) return;
    float dot = 0.f;
    for (int h = 0; h < HID; h++) dot += sums[g * HID + h] * fc_w[h];
    float cnt = counts[g]; if (cnt < 1.f) cnt = 1.f;
    out[g] = dot / cnt + fc_b[0];
}

extern "C" void kernel_launch(void* const* d_in, const int* in_sizes, int n_in,
                              void* d_out, int out_size, void* d_ws, size_t ws_size,
                              hipStream_t stream) {
    const float* x_in      = (const float*)d_in[0];
    const float* edge_attr = (const float*)d_in[1];
    const float* edge_w    = (const float*)d_in[2];
    const float* edge_b    = (const float*)d_in[3];
    const float* node_w    = (const float*)d_in[4];
    const float* node_b    = (const float*)d_in[5];
    const float* fc_w      = (const float*)d_in[6];
    const float* fc_b      = (const float*)d_in[7];
    const int*   edge_index= (const int*)d_in[8];
    const int*   batch     = (const int*)d_in[9];
    float* out = (float*)d_out;

    // workspace layout (4B units):
    // xA[N*H] | xB[N*H] | esrc[E] | rowptr[N+1] | cursor[N] | hist[N] | bsum | boff |
    // sattr[N] | uv | sums | counts
    float* xA     = (float*)d_ws;
    float* xB     = xA + (size_t)N_NODES * HID;
    int*   esrc   = (int*)(xB + (size_t)N_NODES * HID);
    int*   rowptr = esrc + N_EDGES;
    int*   cursor = rowptr + N_NODES + 1;
    int*   hist   = cursor + N_NODES;
    int*   bsum   = hist + N_NODES;
    int*   boff   = bsum + SCAN_NB;
    float* sattr  = (float*)(boff + SCAN_NB);
    float* uv     = sattr + N_NODES;
    float* sums   = uv + N_LAYERS * 2 * HID;
    float* counts = sums + N_GRAPHS * HID;

    const int* src = edge_index;            // edge_index[0]
    const int* dst = edge_index + N_EDGES;  // edge_index[1]

    // zero hist .. counts (contiguous tail region)
    size_t zcount = (size_t)N_NODES + 2 * SCAN_NB + (size_t)N_NODES
                  + N_LAYERS * 2 * HID + (size_t)N_GRAPHS * HID + N_GRAPHS;
    hipMemsetAsync(hist, 0, zcount * sizeof(int), stream);

    uv_kernel<<<1, 256, 0, stream>>>(edge_w, edge_b, node_w, uv);
    edge_stats_kernel<<<(N_EDGES + 255) / 256, 256, 0, stream>>>(dst, edge_attr, hist, sattr);
    scan_bsum_kernel<<<SCAN_NB, SCAN_B, 0, stream>>>(hist, bsum);
    scan_top_kernel<<<1, SCAN_B, 0, stream>>>(bsum, boff);
    scan_apply_kernel<<<SCAN_NB, SCAN_B, 0, stream>>>(hist, boff, rowptr, cursor);
    build_kernel<<<(N_EDGES + 255) / 256, 256, 0, stream>>>(src, dst, cursor, esrc);

    // 3 fused layers, ping-pong x buffers
    const int AGG_WAVES  = (N_NODES + NPW - 1) / NPW;          // 12500
    const int AGG_BLOCKS = (AGG_WAVES + 3) / 4;                // 4 waves/block
    const float* xin = x_in;
    float* bufs[2] = { xA, xB };
    for (int l = 0; l < N_LAYERS; l++) {
        float* xo = bufs[l & 1];
        agg_update_kernel<<<AGG_BLOCKS, 256, 0, stream>>>(
            xin, esrc, rowptr,
            node_w + (size_t)l * 2 * HID * HID, node_b + l * HID, uv + l * 2 * HID,
            sattr, xo);
        xin = xo;
    }

    pool_kernel<<<(N_NODES + 127) / 128, 64, 0, stream>>>(xA, batch, sums, counts);
    final_kernel<<<1, 64, 0, stream>>>(sums, counts, fc_w, fc_b, out);
}